// Round 11
// baseline (425.063 us; speedup 1.0000x reference)
//
#include <hip/hip_runtime.h>
#include <stdint.h>

// VQ argmin, bit-replicating numpy fp32 reference (see R2).
// R11: NO LDS in the hot loop. R6's LDS-bound ceiling (b128 ~12cyc issue,
// banking-independent; 66.4% VALUBusy == 4096/6144 model) is removed by
// reading both operands straight from global/L1 per d (8-lane-shared
// addresses coalesce; z+c rows are L1/L2 resident). 8x8 tile (the only one
// the allocator serves: acc=64 regs fits the 128-VGPR cap of (256,2)).
// No barriers, no DMA, no staging. Grid 1024 (SPLIT=4) -> 4 blocks/CU,
// 16 waves/CU TLP. Per-SIMD/d: VALU 528cyc >> VMEM 256 -> VALU-bound,
// floor ~113us. Epilogue: shfl butterfly + u64-key atomicMin + gather.
// B=16 D=256 H=W=32 -> n=16384 pixels; K=2048 codes.

#define D_    256
#define K_    2048
#define HW_   1024
#define MT    64      // pixels per block
#define SPLIT 4
#define KS    (K_ / SPLIT)   // 512 codes per block slice
#define NPIX  16384

// numpy pairwise combine of 8 accumulators
__device__ __forceinline__ float pw8(const float r[8]) {
    float t01 = __fadd_rn(r[0], r[1]);
    float t23 = __fadd_rn(r[2], r[3]);
    float L   = __fadd_rn(t01, t23);
    float t45 = __fadd_rn(r[4], r[5]);
    float t67 = __fadd_rn(r[6], r[7]);
    float R   = __fadd_rn(t45, t67);
    return __fadd_rn(L, R);
}

// prep: [0,128) transpose cb->ct (+blk0 zeroes cnt); [128,136) Bn;
//       [136,200) An (pairwise exact) + keys init
__global__ __launch_bounds__(256) void prep_k(const float* __restrict__ z,
                                              const float* __restrict__ cb,
                                              float* __restrict__ ct,
                                              float* __restrict__ An,
                                              float* __restrict__ Bn,
                                              unsigned long long* __restrict__ keys,
                                              int* __restrict__ cnt) {
    __shared__ float t[64][65];
    int tid = threadIdx.x;
    int bx  = blockIdx.x;
    if (bx < 128) {
        if (bx == 0) cnt[tid] = 0;           // 256 pixel-blocks
        int k0 = (bx & 31) << 6;
        int d0 = (bx >> 5) << 6;
        #pragma unroll
        for (int it = 0; it < 4; ++it) {
            int u  = (it << 8) + tid;
            int kk = u >> 4;
            int dd = (u & 15) << 2;
            float4 v = *reinterpret_cast<const float4*>(
                cb + (size_t)(k0 + kk) * D_ + d0 + dd);
            t[kk][dd + 0] = v.x; t[kk][dd + 1] = v.y;
            t[kk][dd + 2] = v.z; t[kk][dd + 3] = v.w;
        }
        __syncthreads();
        #pragma unroll
        for (int it = 0; it < 4; ++it) {
            int u  = (it << 8) + tid;
            int dd = u >> 4;
            int kk = (u & 15) << 2;
            float4 o;
            o.x = t[kk + 0][dd]; o.y = t[kk + 1][dd];
            o.z = t[kk + 2][dd]; o.w = t[kk + 3][dd];
            *reinterpret_cast<float4*>(ct + (size_t)(d0 + dd) * K_ + k0 + kk) = o;
        }
    } else if (bx < 136) {
        int row = (bx - 128) * 256 + tid;
        const float4* p = reinterpret_cast<const float4*>(cb + (size_t)row * D_);
        float rA[8], rB[8];
        #pragma unroll
        for (int j = 0; j < 8; ++j) { rA[j] = 0.f; rB[j] = 0.f; }
        #pragma unroll
        for (int q = 0; q < 64; ++q) {
            float4 v = p[q];
            float pv[4] = {__fmul_rn(v.x, v.x), __fmul_rn(v.y, v.y),
                           __fmul_rn(v.z, v.z), __fmul_rn(v.w, v.w)};
            if (q < 32) {
                #pragma unroll
                for (int l = 0; l < 4; ++l)
                    rA[(4 * q + l) & 7] = __fadd_rn(rA[(4 * q + l) & 7], pv[l]);
            } else {
                #pragma unroll
                for (int l = 0; l < 4; ++l)
                    rB[(4 * q + l) & 7] = __fadd_rn(rB[(4 * q + l) & 7], pv[l]);
            }
        }
        Bn[row] = __fadd_rn(pw8(rA), pw8(rB));
    } else {
        int blk = bx - 136;                  // [0,64): 256 pixels each
        int b   = blk >> 2;
        int hw0 = (blk & 3) << 8;
        keys[(size_t)b * HW_ + hw0 + tid] = 0xFFFFFFFFFFFFFFFFull;
        const float* zb = z + (size_t)b * (D_ * HW_) + hw0 + tid;
        float rA[8], rB[8];
        #pragma unroll
        for (int j = 0; j < 8; ++j) { rA[j] = 0.f; rB[j] = 0.f; }
        #pragma unroll 8
        for (int d = 0; d < 128; ++d) {
            float v = zb[(size_t)d * HW_];
            rA[d & 7] = __fadd_rn(rA[d & 7], __fmul_rn(v, v));
        }
        #pragma unroll 8
        for (int d = 128; d < 256; ++d) {
            float v = zb[(size_t)d * HW_];
            rB[d & 7] = __fadd_rn(rB[d & 7], __fmul_rn(v, v));
        }
        An[(size_t)b * HW_ + hw0 + tid] = __fadd_rn(pw8(rA), pw8(rB));
    }
}

// main GEMM+argmin: zero-LDS hot loop, operands from global/L1
__global__ __launch_bounds__(256, 2) void vq_k(const float* __restrict__ z,
                                               const float* __restrict__ ct,
                                               const float* __restrict__ cb,
                                               const float* __restrict__ An,
                                               const float* __restrict__ Bn,
                                               unsigned long long* __restrict__ keys,
                                               int* __restrict__ cnt,
                                               float* __restrict__ out) {
    __shared__ unsigned long long kred[MT * 4];   // 2 KB
    __shared__ int idxs[MT];
    __shared__ int sflag;

    const int tid = threadIdx.x;
    const int w   = tid >> 6;                // wave id [0,4)
    const int u   = tid & 7;                 // code-group within wave (lane&7)
    const int tm  = (tid >> 3) & 7;          // pixel-group within wave
    const int tn  = u | (w << 3);            // [0,32) code-group in block
    const int p   = blockIdx.x >> 2;         // pixel-block [0,256)
    const int s   = blockIdx.x & 3;          // K-split slice
    const int b      = p >> 4;
    const int hwbase = (p & 15) << 6;        // 64 pixels

    // operand base pointers (per-thread; 8 lanes share each address)
    const float* zt = z + (size_t)b * (D_ * HW_) + hwbase + (tm << 3);
    unsigned long long kmin[8];
    #pragma unroll
    for (int i = 0; i < 8; ++i) kmin[i] = 0xFFFFFFFFFFFFFFFFull;

    for (int nc = 0; nc < 2; ++nc) {         // 2 chunks of 256 codes
        const float* cs = ct + s * KS + nc * 256 + (tn << 3);
        float acc[8][8];
        #pragma unroll
        for (int i = 0; i < 8; ++i)
            #pragma unroll
            for (int j = 0; j < 8; ++j) acc[i][j] = 0.f;

        // ascending-d single-acc FMA chain over all 256 dims — bit-matches sgemm
        #pragma unroll 4
        for (int d = 0; d < D_; ++d) {
            const float* zp = zt + (size_t)d * HW_;
            const float* cp = cs + (size_t)d * K_;
            float4 a0 = *reinterpret_cast<const float4*>(zp);
            float4 a1 = *reinterpret_cast<const float4*>(zp + 4);
            float4 b0 = *reinterpret_cast<const float4*>(cp);
            float4 b1 = *reinterpret_cast<const float4*>(cp + 4);
            float av[8] = {a0.x, a0.y, a0.z, a0.w, a1.x, a1.y, a1.z, a1.w};
            float bv[8] = {b0.x, b0.y, b0.z, b0.w, b1.x, b1.y, b1.z, b1.w};
            #pragma unroll
            for (int i = 0; i < 8; ++i)
                #pragma unroll
                for (int j = 0; j < 8; ++j)
                    acc[i][j] = fmaf(av[i], bv[j], acc[i][j]);
        }
        // fold: d = fp32( fp32(A+B) - 2*M ); u64 key = exact (score,idx) min
        #pragma unroll
        for (int j = 0; j < 8; ++j) {
            int ng = s * KS + nc * 256 + (tn << 3) + j;
            float bn = Bn[ng];
            #pragma unroll
            for (int i = 0; i < 8; ++i) {
                float an = An[(size_t)b * HW_ + hwbase + (tm << 3) + i];
                float sc = __fsub_rn(__fadd_rn(an, bn),
                                     __fmul_rn(2.0f, acc[i][j]));
                // sc > 0 always -> fp32 bit pattern order-preserving
                unsigned long long key =
                    ((unsigned long long)__float_as_uint(sc) << 32) | (unsigned)ng;
                if (key < kmin[i]) kmin[i] = key;
            }
        }
    }

    // in-wave butterfly over the 8 u-groups (same pixels, disjoint codes)
    #pragma unroll
    for (int i = 0; i < 8; ++i) {
        unsigned long long k = kmin[i], o;
        o = __shfl_xor(k, 1, 64); if (o < k) k = o;
        o = __shfl_xor(k, 2, 64); if (o < k) k = o;
        o = __shfl_xor(k, 4, 64); if (o < k) k = o;
        kmin[i] = k;
    }
    if (u == 0) {
        #pragma unroll
        for (int i = 0; i < 8; ++i)
            kred[((tm << 3) + i) * 4 + w] = kmin[i];
    }
    __syncthreads();
    unsigned long long* keyp = keys + (size_t)b * HW_ + hwbase;
    if (tid < MT) {
        unsigned long long k2 = kred[tid * 4];
        #pragma unroll
        for (int t = 1; t < 4; ++t) {
            unsigned long long o = kred[tid * 4 + t];
            if (o < k2) k2 = o;
        }
        atomicMin(keyp + tid, k2);
    }
    __threadfence();
    __syncthreads();
    if (tid == 0) sflag = atomicAdd(cnt + p, 1);
    __syncthreads();
    if (sflag == SPLIT - 1) {         // last split: gather + store 64 pixels
        if (tid < MT) {
            unsigned long long v = atomicMin(keyp + tid, 0xFFFFFFFFFFFFFFFFull);
            idxs[tid] = (int)(unsigned)v;
        }
        __syncthreads();
        float* obase = out + (size_t)b * (D_ * HW_) + hwbase;
        #pragma unroll
        for (int it = 0; it < 16; ++it) {
            int uu = (it << 8) + tid;
            int dd = uu >> 4;         // [0,256)
            int c4 = uu & 15;         // float4 column among 64 pixels
            int i0 = idxs[(c4 << 2) + 0];
            int i1 = idxs[(c4 << 2) + 1];
            int i2 = idxs[(c4 << 2) + 2];
            int i3 = idxs[(c4 << 2) + 3];
            float4 o;
            o.x = cb[(size_t)i0 * D_ + dd];
            o.y = cb[(size_t)i1 * D_ + dd];
            o.z = cb[(size_t)i2 * D_ + dd];
            o.w = cb[(size_t)i3 * D_ + dd];
            *reinterpret_cast<float4*>(obase + (size_t)dd * HW_ + (c4 << 2)) = o;
        }
    }
}

extern "C" void kernel_launch(void* const* d_in, const int* in_sizes, int n_in,
                              void* d_out, int out_size, void* d_ws, size_t ws_size,
                              hipStream_t stream) {
    const float* z  = (const float*)d_in[0];   // 16*256*32*32
    const float* cb = (const float*)d_in[1];   // 2048*256
    unsigned long long* keys = (unsigned long long*)d_ws;   // 16384
    int*   cnt = (int*)(keys + NPIX);                       // 256
    float* An  = (float*)(cnt + 256);                       // 16384
    float* Bn  = An + NPIX;                                 // 2048
    float* ct  = Bn + K_;                                   // 256*2048 (2 MB)
    float* out = (float*)d_out;

    prep_k<<<dim3(200), dim3(256), 0, stream>>>(z, cb, ct, An, Bn, keys, cnt);
    vq_k<<<dim3(256 * SPLIT), dim3(256), 0, stream>>>(z, ct, cb, An, Bn,
                                                      keys, cnt, out);
}